// Round 3
// baseline (368.774 us; speedup 1.0000x reference)
//
#include <hip/hip_runtime.h>
#include <hip/hip_bf16.h>
#include <cstdint>
#include <cstddef>

#define HIDN   512
#define NHEADS 8
#define BATCH  8
#define SLEN   4096
#define TLEN   512
#define SSPLIT 4
#define SCHUNK (SLEN / SSPLIT)          // 1024 s per block
#define SCL2   0.18033688f              // 0.125 * log2(e)

typedef __attribute__((ext_vector_type(8))) short   bf16x8;
typedef __attribute__((ext_vector_type(4))) float   f32x4;
typedef unsigned short u16;
typedef unsigned int   u32;

__device__ __forceinline__ u32 pkbf(float a, float b) {
    __hip_bfloat162 h = __float22bfloat162_rn(float2{a, b});
    union { __hip_bfloat162 h; u32 u; } un; un.h = h; return un.u;   // a low
}
__device__ __forceinline__ u16 f2b1(float x) {
    union { float f; u32 u; } a; a.f = x;
    u32 r = (a.u + 0x7fff + ((a.u >> 16) & 1)) >> 16;
    return (u16)r;
}
// async 16B/lane global->LDS; lds ptr must be wave-uniform base, lane i lands
// at base + i*16 (m97 pattern).
__device__ __forceinline__ void gload_lds16(const u16* g, u16* l) {
    __builtin_amdgcn_global_load_lds(
        (const __attribute__((address_space(1))) u32*)g,
        (__attribute__((address_space(3))) u32*)l, 16, 0, 0);
}

// ---------------------------------------------------------------------------
// fp32->bf16 conversion + mask->neg(-1e30) pass.
// float4-unit ranges: X 4194304 | T 524288 | W 262144 | mask 8192
// ---------------------------------------------------------------------------
__global__ __launch_bounds__(256) void cvt_all(
    const float* __restrict__ X, const float* __restrict__ Tg,
    const float* __restrict__ Wq, const float* __restrict__ Wk,
    const float* __restrict__ Wv, const float* __restrict__ Wo,
    const int* __restrict__ mask,
    u16* __restrict__ Xc, u16* __restrict__ Tc, u16* __restrict__ Wc,
    float* __restrict__ negf)
{
    int i4 = blockIdx.x * 256 + threadIdx.x;
    if (i4 >= 4980736) {                       // mask -> neg floats
        int off = i4 - 4980736;
        int4 mv = ((const int4*)mask)[off];
        float4 nv;
        nv.x = mv.x ? 0.f : -1e30f; nv.y = mv.y ? 0.f : -1e30f;
        nv.z = mv.z ? 0.f : -1e30f; nv.w = mv.w ? 0.f : -1e30f;
        ((float4*)negf)[off] = nv;
        return;
    }
    const float* s; u16* d; long off;
    if (i4 < 4194304)      { s = X;  d = Xc; off = i4; }
    else if (i4 < 4718592) { s = Tg; d = Tc; off = i4 - 4194304; }
    else {
        int wi = i4 - 4718592; int widx = wi >> 16;
        s = (widx == 0) ? Wq : (widx == 1) ? Wk : (widx == 2) ? Wv : Wo;
        d = Wc + widx * 262144; off = wi & 65535;
    }
    float4 v = *(const float4*)(s + off * 4);
    uint2 o; o.x = pkbf(v.x, v.y); o.y = pkbf(v.z, v.w);
    *(uint2*)(d + off * 4) = o;
}

// ---------------------------------------------------------------------------
// bf16 MFMA GEMM, Y = A @ W^T + bias, global_load_lds staging (m97 pattern).
// 128x128 tile, BK=32, 256 thr / 4 waves, 4x4 mfma 16x16x32 per wave.
// MODE 0: fp32 Y[n*512+o]; MODE 1: bf16 (B,H,seq,dk); MODE 2: bf16 (B,H,dk,seq)
// ---------------------------------------------------------------------------
template<int MODE, int SEQ>
__global__ __launch_bounds__(256)
void gemm_bf16(const u16* __restrict__ A, const u16* __restrict__ Bw,
               const float* __restrict__ bias, void* __restrict__ Yv)
{
    __shared__ u16 As[128 * 32];   // linear in f: byte addr = f*16
    __shared__ u16 Bs[128 * 32];
    const int tid = threadIdx.x;
    const int lane = tid & 63, w = tid >> 6;
    const int m = lane & 15, qd = lane >> 4;
    const int wm = w >> 1, wn = w & 1;
    const int m0 = blockIdx.y * 128, n0 = blockIdx.x * 128;

    f32x4 acc[4][4];
#pragma unroll
    for (int i = 0; i < 4; ++i)
#pragma unroll
        for (int j = 0; j < 4; ++j) acc[i][j] = (f32x4){0.f, 0.f, 0.f, 0.f};

    for (int k0 = 0; k0 < HIDN; k0 += 32) {
#pragma unroll
        for (int r = 0; r < 2; ++r) {
            const int f = tid + r * 256;
            const int row = f >> 2, c8 = (f & 3) * 8;
            const int fb = f & ~63;            // wave-uniform f base
            gload_lds16(A  + (size_t)(m0 + row) * HIDN + k0 + c8, As + fb * 8);
            gload_lds16(Bw + (size_t)(n0 + row) * HIDN + k0 + c8, Bs + fb * 8);
        }
        __syncthreads();
        bf16x8 af[4], bf[4];
#pragma unroll
        for (int t = 0; t < 4; ++t) {
            af[t] = *(bf16x8*)&As[(64 * wm + 16 * t + m) * 32 + 8 * qd];
            bf[t] = *(bf16x8*)&Bs[(64 * wn + 16 * t + m) * 32 + 8 * qd];
        }
#pragma unroll
        for (int ti = 0; ti < 4; ++ti)
#pragma unroll
            for (int tj = 0; tj < 4; ++tj)
                acc[ti][tj] = __builtin_amdgcn_mfma_f32_16x16x32_bf16(
                    af[ti], bf[tj], acc[ti][tj], 0, 0, 0);
        __syncthreads();
    }

#pragma unroll
    for (int ti = 0; ti < 4; ++ti) {
        const int gr0 = m0 + 64 * wm + 16 * ti + 4 * qd;
#pragma unroll
        for (int tj = 0; tj < 4; ++tj) {
            const int gcol = n0 + 64 * wn + 16 * tj + m;
            const float bv = bias[gcol];
            if (MODE == 0) {
                float* Y = (float*)Yv;
#pragma unroll
                for (int i = 0; i < 4; ++i)
                    Y[(size_t)(gr0 + i) * HIDN + gcol] = acc[ti][tj][i] + bv;
            } else if (MODE == 1) {
                u16* Y = (u16*)Yv;
                const int b = gr0 / SEQ, h = gcol >> 6, d = gcol & 63;
#pragma unroll
                for (int i = 0; i < 4; ++i) {
                    const int r = (gr0 + i) & (SEQ - 1);
                    Y[(((size_t)(b * 8 + h)) * SEQ + r) * 64 + d] =
                        f2b1(acc[ti][tj][i] + bv);
                }
            } else {
                u16* Y = (u16*)Yv;
                const int b = gr0 / SEQ, h = gcol >> 6, d = gcol & 63;
                const int r = gr0 & (SEQ - 1);
                uint2 o;
                o.x = pkbf(acc[ti][tj][0] + bv, acc[ti][tj][1] + bv);
                o.y = pkbf(acc[ti][tj][2] + bv, acc[ti][tj][3] + bv);
                *(uint2*)&Y[(((size_t)(b * 8 + h)) * 64 + d) * SEQ + r] = o;
            }
        }
    }
}

// ---------------------------------------------------------------------------
// Flash attention, barrier-free, max-free softmax, split-S partials.
// Grid (ti=4, si=SSPLIT, bh=64), 256 thr / 4 waves; wave handles 32 t
// (2 strips of 16), t-tile 128/block. All MFMA fragments loaded DIRECTLY
// from global (16B/lane coalesced) -- no LDS, no __syncthreads.
// S^T = K·Q^T per 64-s chunk (lane owns one t per strip); p = exp2(scaled).
// PV via bpermute P-relayout (round-2-verified mapping).
// Partial O (fp32) and l to workspace; combined by attn_combine.
// ---------------------------------------------------------------------------
__global__ __launch_bounds__(256)
void attn_part(const u16* __restrict__ Q, const u16* __restrict__ K,
               const u16* __restrict__ Vt, const float* __restrict__ negf,
               float* __restrict__ Opart, float* __restrict__ lpart)
{
    const int tid = threadIdx.x;
    const int lane = tid & 63, w = tid >> 6;
    const int m = lane & 15, qd = lane >> 4;
    const int ti = blockIdx.x, si = blockIdx.y, bh = blockIdx.z;
    const int b = bh >> 3;

    const u16* Qp = Q + ((size_t)bh * TLEN + ti * 128) * 64;
    const u16* Kp = K + (size_t)bh * SLEN * 64;
    const u16* Vp = Vt + (size_t)bh * 64 * SLEN;
    const float* np = negf + (size_t)b * SLEN;

    bf16x8 qf[2][2];
#pragma unroll
    for (int ts = 0; ts < 2; ++ts)
#pragma unroll
        for (int kh = 0; kh < 2; ++kh)
            qf[ts][kh] = *(const bf16x8*)(Qp + (32 * w + 16 * ts + m) * 64 +
                                          32 * kh + 8 * qd);

    f32x4 O[2][4];
#pragma unroll
    for (int ts = 0; ts < 2; ++ts)
#pragma unroll
        for (int dt = 0; dt < 4; ++dt) O[ts][dt] = (f32x4){0.f, 0.f, 0.f, 0.f};
    float lrun[2] = {0.f, 0.f};
    const int idx0 = (((lane & 16) ? 32 : 0) + m) * 4;
    const int idx1 = idx0 + 64;

    const int s_beg = si * SCHUNK;
    for (int c = 0; c < SCHUNK; c += 64) {
        const int s0 = s_beg + c;
        bf16x8 kf[4][2], vf[4][2];
#pragma unroll
        for (int st = 0; st < 4; ++st)
#pragma unroll
            for (int kh = 0; kh < 2; ++kh)
                kf[st][kh] = *(const bf16x8*)(Kp + (size_t)(s0 + 16 * st + m) * 64 +
                                              32 * kh + 8 * qd);
#pragma unroll
        for (int dt = 0; dt < 4; ++dt)
#pragma unroll
            for (int ks = 0; ks < 2; ++ks)
                vf[dt][ks] = *(const bf16x8*)(Vp + (size_t)(16 * dt + m) * SLEN +
                                              s0 + 32 * ks + 8 * qd);
        float4 negv[4];
#pragma unroll
        for (int st = 0; st < 4; ++st)
            negv[st] = *(const float4*)(np + s0 + 16 * st + 4 * qd);

#pragma unroll
        for (int ts = 0; ts < 2; ++ts) {
            f32x4 S[4];
#pragma unroll
            for (int st = 0; st < 4; ++st) {
                f32x4 cc = (f32x4){0.f, 0.f, 0.f, 0.f};
                cc = __builtin_amdgcn_mfma_f32_16x16x32_bf16(kf[st][0], qf[ts][0], cc, 0, 0, 0);
                cc = __builtin_amdgcn_mfma_f32_16x16x32_bf16(kf[st][1], qf[ts][1], cc, 0, 0, 0);
                S[st] = cc;
            }
            u32 pk[4][2];
            float ls = 0.f;
#pragma unroll
            for (int st = 0; st < 4; ++st) {
                float pv[4];
                pv[0] = exp2f(fmaf(S[st][0], SCL2, negv[st].x));
                pv[1] = exp2f(fmaf(S[st][1], SCL2, negv[st].y));
                pv[2] = exp2f(fmaf(S[st][2], SCL2, negv[st].z));
                pv[3] = exp2f(fmaf(S[st][3], SCL2, negv[st].w));
                ls += pv[0] + pv[1] + pv[2] + pv[3];
                pk[st][0] = pkbf(pv[0], pv[1]);
                pk[st][1] = pkbf(pv[2], pv[3]);
            }
            lrun[ts] += ls;
#pragma unroll
            for (int ks = 0; ks < 2; ++ks) {
                u32 bd[4];
#pragma unroll
                for (int bj = 0; bj < 4; ++bj) {
                    const int j0 = bj & 1;
                    const int idx = (bj >> 1) ? idx1 : idx0;
                    u32 lo = (u32)__builtin_amdgcn_ds_bpermute(idx, (int)pk[2 * ks][j0]);
                    u32 hi = (u32)__builtin_amdgcn_ds_bpermute(idx, (int)pk[2 * ks + 1][j0]);
                    bd[bj] = (lane < 32) ? lo : hi;
                }
                union { uint4 u; bf16x8 v; } bu;
                bu.u = make_uint4(bd[0], bd[1], bd[2], bd[3]);
#pragma unroll
                for (int dt = 0; dt < 4; ++dt)
                    O[ts][dt] = __builtin_amdgcn_mfma_f32_16x16x32_bf16(
                        vf[dt][ks], bu.v, O[ts][dt], 0, 0, 0);
            }
        }
    }

#pragma unroll
    for (int ts = 0; ts < 2; ++ts) {
        float l = lrun[ts];
        l += __shfl_xor(l, 16, 64);
        l += __shfl_xor(l, 32, 64);
        const int tl = 32 * w + 16 * ts + m;
        float* Ob = Opart + ((((size_t)(si * 64 + bh)) * 512 + ti * 128 + tl)) * 64;
#pragma unroll
        for (int dt = 0; dt < 4; ++dt)
            *(f32x4*)&Ob[16 * dt + 4 * qd] = O[ts][dt];
        if (qd == 0)
            lpart[((size_t)(si * 64 + bh)) * 512 + ti * 128 + tl] = l;
    }
}

// ---------------------------------------------------------------------------
// Combine split-S partials: ctx(B,T,512) bf16 = (sum O)/(sum l).
// ---------------------------------------------------------------------------
__global__ __launch_bounds__(256)
void attn_combine(const float* __restrict__ Opart, const float* __restrict__ lpart,
                  u16* __restrict__ ctx)
{
    const int gid = blockIdx.x * 256 + threadIdx.x;   // 524288 = 64bh*512t*16d4
    const int d4 = gid & 15, t = (gid >> 4) & 511, bh = gid >> 13;
    const int b = bh >> 3, h = bh & 7;
    float4 o = {0.f, 0.f, 0.f, 0.f}; float l = 0.f;
#pragma unroll
    for (int si = 0; si < SSPLIT; ++si) {
        const size_t base = ((size_t)(si * 64 + bh)) * 512 + t;
        l += lpart[base];
        const float4 v = *(const float4*)(Opart + base * 64 + d4 * 4);
        o.x += v.x; o.y += v.y; o.z += v.z; o.w += v.w;
    }
    const float r = 1.f / l;
    uint2 pk; pk.x = pkbf(o.x * r, o.y * r); pk.y = pkbf(o.z * r, o.w * r);
    *(uint2*)&ctx[((size_t)(b * 512 + t)) * 512 + h * 64 + d4 * 4] = pk;
}

// ---------------------------------------------------------------------------
extern "C" void kernel_launch(void* const* d_in, const int* in_sizes, int n_in,
                              void* d_out, int out_size, void* d_ws, size_t ws_size,
                              hipStream_t stream)
{
    const float* inputs  = (const float*)d_in[0];
    const float* targets = (const float*)d_in[1];
    const int*   mask    = (const int*)d_in[2];
    const float* Wq = (const float*)d_in[3];
    const float* bq = (const float*)d_in[4];
    const float* Wk = (const float*)d_in[5];
    const float* bk = (const float*)d_in[6];
    const float* Wv = (const float*)d_in[7];
    const float* bv = (const float*)d_in[8];
    const float* Wo = (const float*)d_in[9];
    const float* bo = (const float*)d_in[10];

    char* ws = (char*)d_ws;
    u16*   Xc    = (u16*)(ws);                            // 33,554,432 B
    u16*   Tc    = (u16*)(ws + 33554432);                 //  4,194,304
    u16*   Wc    = (u16*)(ws + 37748736);                 //  2,097,152
    float* negf  = (float*)(ws + 39845888);               //    131,072
    u16*   Qws   = (u16*)(ws + 39976960);                 //  4,194,304
    u16*   Kws   = (u16*)(ws + 44171264);                 // 33,554,432
    u16*   Vtws  = (u16*)(ws + 77725696);                 // 33,554,432
    u16*   Cws   = (u16*)(ws + 111280128);                //  4,194,304
    float* Opart = (float*)(ws + 115474432);              // 33,554,432
    float* lpart = (float*)(ws + 149028864);              //    524,288

    cvt_all<<<19520, 256, 0, stream>>>(inputs, targets, Wq, Wk, Wv, Wo, mask,
                                       Xc, Tc, Wc, negf);

    gemm_bf16<1, TLEN><<<dim3(4, 32),  256, 0, stream>>>(Tc, Wc,           bq, Qws);
    gemm_bf16<1, SLEN><<<dim3(4, 256), 256, 0, stream>>>(Xc, Wc + 262144,  bk, Kws);
    gemm_bf16<2, SLEN><<<dim3(4, 256), 256, 0, stream>>>(Xc, Wc + 524288,  bv, Vtws);

    attn_part<<<dim3(4, SSPLIT, 64), 256, 0, stream>>>(Qws, Kws, Vtws, negf,
                                                       Opart, lpart);
    attn_combine<<<2048, 256, 0, stream>>>(Opart, lpart, Cws);

    gemm_bf16<0, TLEN><<<dim3(4, 32), 256, 0, stream>>>(Cws, Wc + 786432, bo,
                                                        (float*)d_out);
}

// Round 4
// 299.150 us; speedup vs baseline: 1.2327x; 1.2327x over previous
//
#include <hip/hip_runtime.h>
#include <hip/hip_bf16.h>
#include <cstdint>
#include <cstddef>

#define HIDN   512
#define NHEADS 8
#define BATCH  8
#define SLEN   4096
#define TLEN   512
#define SSPLIT 4
#define SCHUNK (SLEN / SSPLIT)          // 1024 s per block
#define SCL2   0.18033688f              // 0.125 * log2(e)

typedef __attribute__((ext_vector_type(8))) short   bf16x8;
typedef __attribute__((ext_vector_type(4))) float   f32x4;
typedef unsigned short u16;
typedef unsigned int   u32;

__device__ __forceinline__ u32 pkbf(float a, float b) {        // accurate RNE
    __hip_bfloat162 h = __float22bfloat162_rn(float2{a, b});
    union { __hip_bfloat162 h; u32 u; } un; un.h = h; return un.u;   // a low
}
// fast 3-op pack (round-half-up): v_add, v_add, v_perm
__device__ __forceinline__ u32 pk2(float a, float b) {
    union { float f; u32 u; } ua, ub; ua.f = a; ub.f = b;
    return __builtin_amdgcn_perm(ub.u + 0x8000u, ua.u + 0x8000u, 0x07060302u);
}
__device__ __forceinline__ void gload_lds16(const u16* g, u16* l) {
    __builtin_amdgcn_global_load_lds(
        (const __attribute__((address_space(1))) u32*)g,
        (__attribute__((address_space(3))) u32*)l, 16, 0, 0);
}

// ---------------------------------------------------------------------------
// fp32->bf16 conversion + mask->neg(-1e30) pass.
// float4-unit ranges: X 4194304 | T 524288 | W 262144 | mask 8192 = 4988928
// ---------------------------------------------------------------------------
__global__ __launch_bounds__(256) void cvt_all(
    const float* __restrict__ X, const float* __restrict__ Tg,
    const float* __restrict__ Wq, const float* __restrict__ Wk,
    const float* __restrict__ Wv, const float* __restrict__ Wo,
    const int* __restrict__ mask,
    u16* __restrict__ Xc, u16* __restrict__ Tc, u16* __restrict__ Wc,
    float* __restrict__ negf)
{
    int i4 = blockIdx.x * 256 + threadIdx.x;
    if (i4 >= 4980736) {
        int off = i4 - 4980736;
        int4 mv = ((const int4*)mask)[off];
        float4 nv;
        nv.x = mv.x ? 0.f : -1e30f; nv.y = mv.y ? 0.f : -1e30f;
        nv.z = mv.z ? 0.f : -1e30f; nv.w = mv.w ? 0.f : -1e30f;
        ((float4*)negf)[off] = nv;
        return;
    }
    const float* s; u16* d; long off;
    if (i4 < 4194304)      { s = X;  d = Xc; off = i4; }
    else if (i4 < 4718592) { s = Tg; d = Tc; off = i4 - 4194304; }
    else {
        int wi = i4 - 4718592; int widx = wi >> 16;
        s = (widx == 0) ? Wq : (widx == 1) ? Wk : (widx == 2) ? Wv : Wo;
        d = Wc + widx * 262144; off = wi & 65535;
    }
    float4 v = *(const float4*)(s + off * 4);
    uint2 o; o.x = pkbf(v.x, v.y); o.y = pkbf(v.z, v.w);
    *(uint2*)(d + off * 4) = o;
}

// ---------------------------------------------------------------------------
// GEMM A-orientation: Y = A @ W^T + bias, A rows staged as MFMA-A.
// MODE 0: fp32 Y[n*512+o] (out-proj).  MODE 2: bf16 (B,H,dk,seq) = V^T,
// uint2 (4 consecutive seq) stores.
// ---------------------------------------------------------------------------
template<int MODE, int SEQ>
__global__ __launch_bounds__(256)
void gemm_bf16(const u16* __restrict__ A, const u16* __restrict__ Bw,
               const float* __restrict__ bias, void* __restrict__ Yv)
{
    __shared__ u16 As[128 * 32];
    __shared__ u16 Bs[128 * 32];
    const int tid = threadIdx.x;
    const int lane = tid & 63, w = tid >> 6;
    const int m = lane & 15, qd = lane >> 4;
    const int wm = w >> 1, wn = w & 1;
    const int m0 = blockIdx.y * 128, n0 = blockIdx.x * 128;

    f32x4 acc[4][4];
#pragma unroll
    for (int i = 0; i < 4; ++i)
#pragma unroll
        for (int j = 0; j < 4; ++j) acc[i][j] = (f32x4){0.f, 0.f, 0.f, 0.f};

    for (int k0 = 0; k0 < HIDN; k0 += 32) {
#pragma unroll
        for (int r = 0; r < 2; ++r) {
            const int f = tid + r * 256;
            const int row = f >> 2, c8 = (f & 3) * 8;
            const int fb = f & ~63;
            gload_lds16(A  + (size_t)(m0 + row) * HIDN + k0 + c8, As + fb * 8);
            gload_lds16(Bw + (size_t)(n0 + row) * HIDN + k0 + c8, Bs + fb * 8);
        }
        __syncthreads();
        bf16x8 af[4], bf[4];
#pragma unroll
        for (int t = 0; t < 4; ++t) {
            af[t] = *(bf16x8*)&As[(64 * wm + 16 * t + m) * 32 + 8 * qd];
            bf[t] = *(bf16x8*)&Bs[(64 * wn + 16 * t + m) * 32 + 8 * qd];
        }
#pragma unroll
        for (int ti = 0; ti < 4; ++ti)
#pragma unroll
            for (int tj = 0; tj < 4; ++tj)
                acc[ti][tj] = __builtin_amdgcn_mfma_f32_16x16x32_bf16(
                    af[ti], bf[tj], acc[ti][tj], 0, 0, 0);
        __syncthreads();
    }

#pragma unroll
    for (int ti = 0; ti < 4; ++ti) {
        const int gr0 = m0 + 64 * wm + 16 * ti + 4 * qd;
#pragma unroll
        for (int tj = 0; tj < 4; ++tj) {
            const int gcol = n0 + 64 * wn + 16 * tj + m;
            const float bv = bias[gcol];
            if (MODE == 0) {
                float* Y = (float*)Yv;
#pragma unroll
                for (int i = 0; i < 4; ++i)
                    Y[(size_t)(gr0 + i) * HIDN + gcol] = acc[ti][tj][i] + bv;
            } else {
                u16* Y = (u16*)Yv;
                const int b = gr0 / SEQ, h = gcol >> 6, d = gcol & 63;
                const int r = gr0 & (SEQ - 1);
                uint2 o;
                o.x = pkbf(acc[ti][tj][0] + bv, acc[ti][tj][1] + bv);
                o.y = pkbf(acc[ti][tj][2] + bv, acc[ti][tj][3] + bv);
                *(uint2*)&Y[(((size_t)(b * 8 + h)) * 64 + d) * SEQ + r] = o;
            }
        }
    }
}

// ---------------------------------------------------------------------------
// GEMM W-orientation (for Q,K projections): C[o][sample] = W·X^T + bias.
// C rows = output channel o -> each lane holds 4 consecutive d (head dim)
// -> coalesced uint2 bf16 stores into (B,H,seq,64).
// ---------------------------------------------------------------------------
template<int SEQ>
__global__ __launch_bounds__(256)
void gemm_wxT(const u16* __restrict__ Wm, const u16* __restrict__ X,
              const float* __restrict__ bias, u16* __restrict__ Y)
{
    __shared__ u16 As[128 * 32];   // W rows (o)
    __shared__ u16 Bs[128 * 32];   // X rows (samples)
    const int tid = threadIdx.x;
    const int lane = tid & 63, w = tid >> 6;
    const int m = lane & 15, qd = lane >> 4;
    const int wm = w >> 1, wn = w & 1;
    const int m0 = blockIdx.y * 128, n0 = blockIdx.x * 128;

    f32x4 acc[4][4];
#pragma unroll
    for (int i = 0; i < 4; ++i)
#pragma unroll
        for (int j = 0; j < 4; ++j) acc[i][j] = (f32x4){0.f, 0.f, 0.f, 0.f};

    for (int k0 = 0; k0 < HIDN; k0 += 32) {
#pragma unroll
        for (int r = 0; r < 2; ++r) {
            const int f = tid + r * 256;
            const int row = f >> 2, c8 = (f & 3) * 8;
            const int fb = f & ~63;
            gload_lds16(Wm + (size_t)(m0 + row) * HIDN + k0 + c8, As + fb * 8);
            gload_lds16(X  + (size_t)(n0 + row) * HIDN + k0 + c8, Bs + fb * 8);
        }
        __syncthreads();
        bf16x8 af[4], bf[4];
#pragma unroll
        for (int t = 0; t < 4; ++t) {
            af[t] = *(bf16x8*)&As[(64 * wm + 16 * t + m) * 32 + 8 * qd];
            bf[t] = *(bf16x8*)&Bs[(64 * wn + 16 * t + m) * 32 + 8 * qd];
        }
#pragma unroll
        for (int ti = 0; ti < 4; ++ti)
#pragma unroll
            for (int tj = 0; tj < 4; ++tj)
                acc[ti][tj] = __builtin_amdgcn_mfma_f32_16x16x32_bf16(
                    af[ti], bf[tj], acc[ti][tj], 0, 0, 0);
        __syncthreads();
    }

#pragma unroll
    for (int ti = 0; ti < 4; ++ti) {
        const int o = m0 + 64 * wm + 16 * ti + 4 * qd;      // 4-aligned
        const float4 bv = *(const float4*)&bias[o];
        const int h = o >> 6, d0 = o & 63;
#pragma unroll
        for (int tj = 0; tj < 4; ++tj) {
            const int n = n0 + 64 * wn + 16 * tj + m;       // sample
            const int b = n / SEQ, r = n & (SEQ - 1);
            uint2 pk;
            pk.x = pkbf(acc[ti][tj][0] + bv.x, acc[ti][tj][1] + bv.y);
            pk.y = pkbf(acc[ti][tj][2] + bv.z, acc[ti][tj][3] + bv.w);
            *(uint2*)&Y[(((size_t)(b * 8 + h)) * SEQ + r) * 64 + d0] = pk;
        }
    }
}

// ---------------------------------------------------------------------------
// Flash attention: barrier-free, max-free softmax, split-S partials.
// Grid (ti=2, si=4, bh=64), 256 thr / 4 waves; wave owns 64 t (4 strips).
// Direct-global MFMA frags via running pointers + imm offsets.
// P relayout C->B via per-wave LDS round-trip (XOR-swizzled, no barriers).
// ---------------------------------------------------------------------------
__global__ __launch_bounds__(256, 2)
void attn_part(const u16* __restrict__ Q, const u16* __restrict__ K,
               const u16* __restrict__ Vt, const float* __restrict__ negf,
               float* __restrict__ Opart, float* __restrict__ lpart)
{
    __shared__ char Psh[32768];   // 4 waves x 4 ts x 2KB
    const int tid = threadIdx.x;
    const int lane = tid & 63, w = tid >> 6;
    const int m = lane & 15, qd = lane >> 4;
    const int ti = blockIdx.x, si = blockIdx.y, bh = blockIdx.z;
    const int b = bh >> 3;

    const u16* Qp = Q + ((size_t)bh * TLEN + ti * 256) * 64;
    const u16* Kp = K + (size_t)bh * SLEN * 64;
    const u16* Vp = Vt + (size_t)bh * 64 * SLEN;
    const float* np = negf + (size_t)b * SLEN;

    // LDS addresses: row t=m (128B), 8B units XOR-swizzled by m -> conflict-free
    const int wb = w * 8192 + m * 128;
    int waddr[4], ra0[2], ra1[2];
#pragma unroll
    for (int st = 0; st < 4; ++st) waddr[st] = wb + (((4 * st + qd) ^ m) << 3);
#pragma unroll
    for (int ks = 0; ks < 2; ++ks) {
        const int u0 = 8 * ks + 2 * qd;
        ra0[ks] = wb + (((u0) ^ m) << 3);
        ra1[ks] = wb + (((u0 + 1) ^ m) << 3);
    }

    bf16x8 qf[4][2];
#pragma unroll
    for (int ts = 0; ts < 4; ++ts)
#pragma unroll
        for (int kh = 0; kh < 2; ++kh)
            qf[ts][kh] = *(const bf16x8*)(Qp + (64 * w + 16 * ts + m) * 64 +
                                          32 * kh + 8 * qd);

    f32x4 O[4][4];
#pragma unroll
    for (int ts = 0; ts < 4; ++ts)
#pragma unroll
        for (int dt = 0; dt < 4; ++dt) O[ts][dt] = (f32x4){0.f, 0.f, 0.f, 0.f};
    float lr[4] = {0.f, 0.f, 0.f, 0.f};

    const int s_beg = si * SCHUNK;
    const u16* kp = Kp + (size_t)(s_beg + m) * 64 + 8 * qd;   // st*1024+kh*32 imm
    const u16* vp0 = Vp + (size_t)m * SLEN + s_beg + 8 * qd;  // ks*32 imm
    const u16* vp1 = vp0 + (size_t)16 * SLEN;
    const u16* vp2 = vp0 + (size_t)32 * SLEN;
    const u16* vp3 = vp0 + (size_t)48 * SLEN;
    const float* npp = np + s_beg + 4 * qd;                   // st*16 imm

#pragma unroll 1
    for (int c = 0; c < SCHUNK; c += 64) {
        bf16x8 kf[4][2];
        kf[0][0] = *(const bf16x8*)(kp + 0);
        kf[0][1] = *(const bf16x8*)(kp + 32);
        kf[1][0] = *(const bf16x8*)(kp + 1024);
        kf[1][1] = *(const bf16x8*)(kp + 1056);
        kf[2][0] = *(const bf16x8*)(kp + 2048);
        kf[2][1] = *(const bf16x8*)(kp + 2080);
        kf[3][0] = *(const bf16x8*)(kp + 3072);
        kf[3][1] = *(const bf16x8*)(kp + 3104);
        float4 ng[4];
        ng[0] = *(const float4*)(npp + 0);
        ng[1] = *(const float4*)(npp + 16);
        ng[2] = *(const float4*)(npp + 32);
        ng[3] = *(const float4*)(npp + 48);
        bf16x8 vf[4][2];
        vf[0][0] = *(const bf16x8*)(vp0 + 0);
        vf[0][1] = *(const bf16x8*)(vp0 + 32);
        vf[1][0] = *(const bf16x8*)(vp1 + 0);
        vf[1][1] = *(const bf16x8*)(vp1 + 32);
        vf[2][0] = *(const bf16x8*)(vp2 + 0);
        vf[2][1] = *(const bf16x8*)(vp2 + 32);
        vf[3][0] = *(const bf16x8*)(vp3 + 0);
        vf[3][1] = *(const bf16x8*)(vp3 + 32);

#pragma unroll
        for (int ts = 0; ts < 4; ++ts) {
            f32x4 S[4];
#pragma unroll
            for (int st = 0; st < 4; ++st) {
                f32x4 cc = (f32x4){0.f, 0.f, 0.f, 0.f};
                cc = __builtin_amdgcn_mfma_f32_16x16x32_bf16(kf[st][0], qf[ts][0], cc, 0, 0, 0);
                cc = __builtin_amdgcn_mfma_f32_16x16x32_bf16(kf[st][1], qf[ts][1], cc, 0, 0, 0);
                S[st] = cc;
            }
            float ls = 0.f;
#pragma unroll
            for (int st = 0; st < 4; ++st) {
                const float p0 = exp2f(fmaf(S[st][0], SCL2, ng[st].x));
                const float p1 = exp2f(fmaf(S[st][1], SCL2, ng[st].y));
                const float p2 = exp2f(fmaf(S[st][2], SCL2, ng[st].z));
                const float p3 = exp2f(fmaf(S[st][3], SCL2, ng[st].w));
                ls += (p0 + p1) + (p2 + p3);
                *(uint2*)&Psh[waddr[st] + ts * 2048] =
                    make_uint2(pk2(p0, p1), pk2(p2, p3));
            }
            lr[ts] += ls;
#pragma unroll
            for (int ks = 0; ks < 2; ++ks) {
                const uint2 r0 = *(uint2*)&Psh[ra0[ks] + ts * 2048];
                const uint2 r1 = *(uint2*)&Psh[ra1[ks] + ts * 2048];
                union { uint4 u; bf16x8 v; } bu;
                bu.u = make_uint4(r0.x, r0.y, r1.x, r1.y);
                O[ts][0] = __builtin_amdgcn_mfma_f32_16x16x32_bf16(vf[0][ks], bu.v, O[ts][0], 0, 0, 0);
                O[ts][1] = __builtin_amdgcn_mfma_f32_16x16x32_bf16(vf[1][ks], bu.v, O[ts][1], 0, 0, 0);
                O[ts][2] = __builtin_amdgcn_mfma_f32_16x16x32_bf16(vf[2][ks], bu.v, O[ts][2], 0, 0, 0);
                O[ts][3] = __builtin_amdgcn_mfma_f32_16x16x32_bf16(vf[3][ks], bu.v, O[ts][3], 0, 0, 0);
            }
        }
        kp += 4096; vp0 += 64; vp1 += 64; vp2 += 64; vp3 += 64; npp += 64;
    }

#pragma unroll
    for (int ts = 0; ts < 4; ++ts) {
        float l = lr[ts];
        l += __shfl_xor(l, 16, 64);
        l += __shfl_xor(l, 32, 64);
        const int t = ti * 256 + 64 * w + 16 * ts + m;
        float* Ob = Opart + (((size_t)(si * 64 + bh)) * 512 + t) * 64;
#pragma unroll
        for (int dt = 0; dt < 4; ++dt)
            *(f32x4*)&Ob[16 * dt + 4 * qd] = O[ts][dt];
        if (qd == 0)
            lpart[((size_t)(si * 64 + bh)) * 512 + t] = l;
    }
}

// ---------------------------------------------------------------------------
// Combine split-S partials: ctx(B,T,512) bf16 = (sum O)/(sum l).
// ---------------------------------------------------------------------------
__global__ __launch_bounds__(256)
void attn_combine(const float* __restrict__ Opart, const float* __restrict__ lpart,
                  u16* __restrict__ ctx)
{
    const int gid = blockIdx.x * 256 + threadIdx.x;
    const int d4 = gid & 15, t = (gid >> 4) & 511, bh = gid >> 13;
    const int b = bh >> 3, h = bh & 7;
    float4 o = {0.f, 0.f, 0.f, 0.f}; float l = 0.f;
#pragma unroll
    for (int si = 0; si < SSPLIT; ++si) {
        const size_t base = ((size_t)(si * 64 + bh)) * 512 + t;
        l += lpart[base];
        const float4 v = *(const float4*)(Opart + base * 64 + d4 * 4);
        o.x += v.x; o.y += v.y; o.z += v.z; o.w += v.w;
    }
    const float r = 1.f / l;
    uint2 pk; pk.x = pkbf(o.x * r, o.y * r); pk.y = pkbf(o.z * r, o.w * r);
    *(uint2*)&ctx[((size_t)(b * 512 + t)) * 512 + h * 64 + d4 * 4] = pk;
}

// ---------------------------------------------------------------------------
extern "C" void kernel_launch(void* const* d_in, const int* in_sizes, int n_in,
                              void* d_out, int out_size, void* d_ws, size_t ws_size,
                              hipStream_t stream)
{
    const float* inputs  = (const float*)d_in[0];
    const float* targets = (const float*)d_in[1];
    const int*   mask    = (const int*)d_in[2];
    const float* Wq = (const float*)d_in[3];
    const float* bq = (const float*)d_in[4];
    const float* Wk = (const float*)d_in[5];
    const float* bk = (const float*)d_in[6];
    const float* Wv = (const float*)d_in[7];
    const float* bv = (const float*)d_in[8];
    const float* Wo = (const float*)d_in[9];
    const float* bo = (const float*)d_in[10];

    char* ws = (char*)d_ws;
    u16*   Xc    = (u16*)(ws);                            // 33,554,432 B
    u16*   Tc    = (u16*)(ws + 33554432);                 //  4,194,304
    u16*   Wc    = (u16*)(ws + 37748736);                 //  2,097,152
    float* negf  = (float*)(ws + 39845888);               //    131,072
    u16*   Qws   = (u16*)(ws + 39976960);                 //  4,194,304
    u16*   Kws   = (u16*)(ws + 44171264);                 // 33,554,432
    u16*   Vtws  = (u16*)(ws + 77725696);                 // 33,554,432
    u16*   Cws   = (u16*)(ws + 111280128);                //  4,194,304
    float* Opart = (float*)(ws + 115474432);              // 33,554,432
    float* lpart = (float*)(ws + 149028864);              //    524,288

    cvt_all<<<19488, 256, 0, stream>>>(inputs, targets, Wq, Wk, Wv, Wo, mask,
                                       Xc, Tc, Wc, negf);

    // Q,K: W-orientation (coalesced head-dim stores)
    gemm_wxT<TLEN><<<dim3(32, 4),  256, 0, stream>>>(Wc,          Tc, bq, Qws);
    gemm_wxT<SLEN><<<dim3(256, 4), 256, 0, stream>>>(Wc + 262144, Xc, bk, Kws);
    // V^T: A-orientation MODE 2
    gemm_bf16<2, SLEN><<<dim3(4, 256), 256, 0, stream>>>(Xc, Wc + 524288, bv, Vtws);

    attn_part<<<dim3(2, SSPLIT, 64), 256, 0, stream>>>(Qws, Kws, Vtws, negf,
                                                       Opart, lpart);
    attn_combine<<<2048, 256, 0, stream>>>(Opart, lpart, Cws);

    gemm_bf16<0, TLEN><<<dim3(4, 32), 256, 0, stream>>>(Cws, Wc + 786432, bo,
                                                        (float*)d_out);
}